// Round 10
// baseline (204.753 us; speedup 1.0000x reference)
//
#include <hip/hip_runtime.h>
#include <hip/hip_bf16.h>

#define T_STEPS 512
#define BATCH 32
#define NST 64
#define DIM 1024

typedef _Float16 f16x8 __attribute__((ext_vector_type(8)));
typedef _Float16 f16x4 __attribute__((ext_vector_type(4)));
typedef float f32x4 __attribute__((ext_vector_type(4)));
typedef float f32x2 __attribute__((ext_vector_type(2)));

__device__ __forceinline__ void gl_lds16(const void* g, void* l) {
  __builtin_amdgcn_global_load_lds(
      (const __attribute__((address_space(1))) void*)g,
      (__attribute__((address_space(3))) void*)l, 16, 0, 0);
}

// ---------------- W concat + fp16 convert ----------------
__global__ __launch_bounds__(256) void wconv(
    const float* __restrict__ Wk, const float* __restrict__ Wv,
    const float* __restrict__ Wq, const float* __restrict__ Wa,
    _Float16* __restrict__ Wc) {
  const int n = blockIdx.x;
  const int g = n >> 6, r = n & 63;
  const float* W = (g == 0) ? Wk : (g == 1) ? Wq : (g == 2) ? Wv : Wa;
  const float sc = (g == 3) ? -1.44269504088896340736f : 1.0f;
  float4 v = *(const float4*)(W + (size_t)r * DIM + threadIdx.x * 4);
  f16x4 h = {(_Float16)(v.x * sc), (_Float16)(v.y * sc), (_Float16)(v.z * sc),
             (_Float16)(v.w * sc)};
  *(f16x4*)(Wc + (size_t)n * DIM + threadIdx.x * 4) = h;
}

// ---------------- Projection GEMM v2 (fp32 output) ----------------
__global__ __launch_bounds__(512) void proj_gemm(
    const float* __restrict__ x, const _Float16* __restrict__ Wc,
    float* __restrict__ projf) {
  const int m0 = blockIdx.x * 64;
  const int tid = threadIdx.x;
  const int lane = tid & 63, wv = tid >> 6;
  const int wm = wv >> 2, wn = wv & 3;
  const int fm = lane & 15, fq = lane >> 4;

  __shared__ __align__(16) _Float16 Bl[2][256 * 32];  // 2 x 16 KB
  __shared__ __align__(16) _Float16 Al[2][64 * 32];   // 2 x 4 KB

  const int brow = tid >> 2;
  const int bcg = (tid & 3) ^ ((tid >> 3) & 3);
  const _Float16* gB = Wc + (size_t)brow * DIM + bcg * 8;
  const int bdst = tid * 8;

#define STAGE_B(buf, k0)                                          \
  {                                                               \
    _Pragma("unroll") for (int i = 0; i < 2; ++i)                 \
        gl_lds16(gB + (size_t)i * 128 * DIM + (k0),               \
                 &Bl[buf][i * 4096 + bdst]);                      \
  }

  const int arow = tid >> 3;
  const int afc = (tid & 7) * 4;
  const float* gA = x + (size_t)(m0 + arow) * DIM + afc;
  const int awp = arow * 32 + ((((tid >> 1) & 3) ^ ((arow >> 1) & 3)) * 8) +
                  (tid & 1) * 4;

#define LOADX(rr, k0)                          \
  {                                            \
    rr = *(const float4*)(gA + (k0));          \
  }
#define CVT_WRITE_A(buf, rr)                                        \
  {                                                                 \
    f16x4 h = {(_Float16)rr.x, (_Float16)rr.y, (_Float16)rr.z,      \
               (_Float16)rr.w};                                     \
    *(f16x4*)&Al[buf][awp] = h;                                     \
  }

  f32x4 acc[2][4];
#pragma unroll
  for (int mi = 0; mi < 2; ++mi)
#pragma unroll
    for (int ni = 0; ni < 4; ++ni) acc[mi][ni] = (f32x4){0.f, 0.f, 0.f, 0.f};

  const int aswz = (fq ^ ((fm >> 1) & 3)) * 8;
  const int abase = (wm * 32 + fm) * 32 + aswz;
  const int bbase = (wn * 64 + fm) * 32 + aswz;

#define COMPUTE(cb)                                                     \
  {                                                                     \
    f16x8 afr[2], bfr[4];                                               \
    _Pragma("unroll") for (int mi = 0; mi < 2; ++mi)                    \
        afr[mi] = *(const f16x8*)&Al[cb][abase + mi * 16 * 32];         \
    _Pragma("unroll") for (int ni = 0; ni < 4; ++ni)                    \
        bfr[ni] = *(const f16x8*)&Bl[cb][bbase + ni * 16 * 32];         \
    _Pragma("unroll") for (int mi = 0; mi < 2; ++mi)                    \
        _Pragma("unroll") for (int ni = 0; ni < 4; ++ni)                \
            acc[mi][ni] = __builtin_amdgcn_mfma_f32_16x16x32_f16(       \
                afr[mi], bfr[ni], acc[mi][ni], 0, 0, 0);                \
  }

  float4 rE, rO;
  LOADX(rE, 0);
  STAGE_B(0, 0);
  LOADX(rO, 32);
  CVT_WRITE_A(0, rE);
  __syncthreads();

  for (int k2 = 0; k2 < 16; ++k2) {
    STAGE_B(1, (2 * k2 + 1) * 32);
    if (k2 < 15) LOADX(rE, (2 * k2 + 2) * 32);
    CVT_WRITE_A(1, rO);
    COMPUTE(0);
    __syncthreads();
    if (k2 < 15) {
      STAGE_B(0, (2 * k2 + 2) * 32);
      LOADX(rO, (2 * k2 + 3) * 32);
      CVT_WRITE_A(0, rE);
    }
    COMPUTE(1);
    __syncthreads();
  }
#undef STAGE_B
#undef LOADX
#undef CVT_WRITE_A
#undef COMPUTE

#pragma unroll
  for (int mi = 0; mi < 2; ++mi)
#pragma unroll
    for (int ni = 0; ni < 4; ++ni) {
      const int gcol = wn * 64 + ni * 16 + fm;
      const int pcol = gcol < 128 ? gcol
                     : (gcol < 192 ? 128 + 2 * (gcol - 128) : 129 + 2 * (gcol - 192));
#pragma unroll
      for (int r = 0; r < 4; ++r) {
        const int grow = m0 + wm * 32 + mi * 16 + fq * 4 + r;
        projf[(size_t)grow * 256 + pcol] = acc[mi][ni][r];
      }
    }
}

// ---------------- Sequential scan v7: cross-phase REGISTER prefetch -------
// R9's one-barrier-per-chunk structure, plus: each role prefetches the NEXT
// chunk's operands from LDS into registers DURING the current phase. ds_reads
// cannot be sunk past s_barrier, so the compiler must hold them in VGPRs ->
// every phase opens with zero memory waits (R9's VGPR=44 proved the "bulk
// load" was being re-sunk into the loop, leaving ~250cy lgkm wait per phase).
// Ordering: producer = prefetch-issue first, then pure-reg compute (reads
// complete under ~1000cy of compute). Consumer = alcc+replay first, prefetch
// last (its exposed tail hides under the producer's longer phase).
// Producer chain refactor (exact): cc = al*(e*v); S_new = al*(S + (e*v)*k)
// -- the w-fma runs parallel with rcp; S-update is one pk_mul after al.
__device__ __forceinline__ float red16(float x) {
  int v = __builtin_amdgcn_update_dpp(0, __float_as_int(x), 0xB1, 0xF, 0xF, true);
  x += __int_as_float(v);
  v = __builtin_amdgcn_update_dpp(0, __float_as_int(x), 0x4E, 0xF, 0xF, true);
  x += __int_as_float(v);
  v = __builtin_amdgcn_update_dpp(0, __float_as_int(x), 0x124, 0xF, 0xF, true);
  x += __int_as_float(v);
  v = __builtin_amdgcn_update_dpp(0, __float_as_int(x), 0x128, 0xF, 0xF, true);
  x += __int_as_float(v);
  return x;
}

__global__ __launch_bounds__(512, 1) void scan_kernel(
    const float* __restrict__ projf, const float* __restrict__ S0,
    const float* __restrict__ d_alpha, const float* __restrict__ b_alpha,
    float* __restrict__ out, float* __restrict__ Sout) {
  const int b = blockIdx.x >> 2;
  const int rg = blockIdx.x & 3;
  const int tid = threadIdx.x;
  const bool prod = tid < 256;
  const int ptid = tid & 255;
  const int c = ptid & 15;           // column lane
  const int lr = ptid >> 4;          // local row 0..15
  const int r = rg * 16 + lr;
  const int j0 = c * 4;

  __shared__ __align__(16) float lbuf[4][2048];    // 4-ring x (8 x 256) f32
  __shared__ __align__(16) float2 alcc[2][16][8];  // [buf][lr][si], 2 KB

  constexpr float NL2E = -1.44269504088896340736f;
  f32x2 s01, s23;
  {
    float4 v = *(const float4*)(S0 + ((size_t)b * NST + r) * NST + j0);
    s01 = (f32x2){v.x, v.y}; s23 = (f32x2){v.z, v.w};
  }
  const float da2 = d_alpha[r] * NL2E;
  const float ba2 = b_alpha[r] * NL2E;

  // staging: 512 threads x 1 float4 = one 8-step chunk (8 KB)
  const int sstep = tid >> 6;         // 0..7
  const int soff = (tid & 63) * 4;    // 0..252
  const int lidx = sstep * 256 + soff;
  const float* gp = projf + (size_t)b * 256;
#define GADDR(ch) (gp + (size_t)((ch) * 8 + sstep) * (BATCH * 256) + soff)

  // register chunk buffers (A = even chunks, B = odd chunks)
  float4 kA[8], kB[8];   // prod: k ; cons: k
  float2 vA[8], vB[8];   // prod: (v, ax)
  float4 qA[8], qB[8];   // cons: q
  float ys[8];           // cons: pending gated outputs

#define P_PREF(kX, vX, slot)                                            \
  {                                                                     \
    const float* Pn = &lbuf[slot][0];                                   \
    _Pragma("unroll") for (int si = 0; si < 8; ++si) {                  \
      kX[si] = *(const float4*)(Pn + si * 256 + j0);                    \
      vX[si] = *(const float2*)(Pn + si * 256 + 128 + 2 * r);           \
    }                                                                   \
  }
#define C_PREF(kX, qX, slot)                                            \
  {                                                                     \
    const float* Pn = &lbuf[slot][0];                                   \
    _Pragma("unroll") for (int si = 0; si < 8; ++si) {                  \
      kX[si] = *(const float4*)(Pn + si * 256 + j0);                    \
      qX[si] = *(const float4*)(Pn + si * 256 + 64 + j0);               \
    }                                                                   \
  }
#define P_COMP(kX, vX, abuf)                                            \
  {                                                                     \
    float alv[8], ccv[8];                                               \
    _Pragma("unroll") for (int si = 0; si < 8; ++si) {                  \
      const f32x2 k01 = {kX[si].x, kX[si].y};                           \
      const f32x2 k23 = {kX[si].z, kX[si].w};                           \
      f32x2 pa = s01 * k01 + s23 * k23;                                 \
      const float rr = red16(pa[0] + pa[1]);                            \
      float z2 = fmaf(da2, rr, vX[si].y + ba2);                         \
      z2 = __builtin_amdgcn_fmed3f(z2, -43.3f, 43.3f);                  \
      const float e = __builtin_amdgcn_exp2f(z2);       /* exp(-z) */   \
      const float ev = e * vX[si].x;                                    \
      const f32x2 ev2 = {ev, ev};                                       \
      const f32x2 w01 = s01 + ev2 * k01;  /* parallel with rcp */       \
      const f32x2 w23 = s23 + ev2 * k23;                                \
      const float al = __builtin_amdgcn_rcpf(1.f + e);  /* sigmoid */   \
      const f32x2 al2 = {al, al};                                       \
      s01 = al2 * w01;                    /* = al*S + (1-al)*v*k */     \
      s23 = al2 * w23;                                                  \
      alv[si] = al; ccv[si] = al * ev;    /* cc = (1-al)*v */           \
    }                                                                   \
    if (c == 0) {                                                       \
      float4 w0 = {alv[0], ccv[0], alv[1], ccv[1]};                     \
      float4 w1 = {alv[2], ccv[2], alv[3], ccv[3]};                     \
      float4 w2 = {alv[4], ccv[4], alv[5], ccv[5]};                     \
      float4 w3 = {alv[6], ccv[6], alv[7], ccv[7]};                     \
      float4* wp = (float4*)&alcc[abuf][lr][0];                         \
      wp[0] = w0; wp[1] = w1; wp[2] = w2; wp[3] = w3;                   \
    }                                                                   \
  }
#define C_COMP(kX, qX, abuf)                                            \
  {                                                                     \
    const float4* ap = (const float4*)&alcc[abuf][lr][0];               \
    float4 a0 = ap[0], a1 = ap[1], a2 = ap[2], a3 = ap[3];              \
    float2 acv[8];                                                      \
    acv[0] = make_float2(a0.x, a0.y); acv[1] = make_float2(a0.z, a0.w); \
    acv[2] = make_float2(a1.x, a1.y); acv[3] = make_float2(a1.z, a1.w); \
    acv[4] = make_float2(a2.x, a2.y); acv[5] = make_float2(a2.z, a2.w); \
    acv[6] = make_float2(a3.x, a3.y); acv[7] = make_float2(a3.z, a3.w); \
    _Pragma("unroll") for (int si = 0; si < 8; ++si) {                  \
      const f32x2 k01 = {kX[si].x, kX[si].y};                           \
      const f32x2 k23 = {kX[si].z, kX[si].w};                           \
      const f32x2 al2 = {acv[si].x, acv[si].x};                         \
      const f32x2 cc2 = {acv[si].y, acv[si].y};                         \
      s01 = al2 * s01 + cc2 * k01;                                      \
      s23 = al2 * s23 + cc2 * k23;                                      \
      const f32x2 q01 = {qX[si].x, qX[si].y};                           \
      const f32x2 q23 = {qX[si].z, qX[si].w};                           \
      f32x2 hh = s01 * q01 + s23 * q23;                                 \
      const float h = red16(hh[0] + hh[1]);                             \
      const float sg =                                                  \
          __builtin_amdgcn_rcpf(1.f + __builtin_amdgcn_exp2f(h * NL2E)); \
      ys[si] = (h * h) * sg;                                            \
    }                                                                   \
  }
#define C_STORE(pc)                                                     \
  {                                                                     \
    if (c == 0) {                                                       \
      _Pragma("unroll") for (int si = 0; si < 8; ++si)                  \
          out[((size_t)((pc) * 8 + si) * BATCH + b) * NST + r] = ys[si]; \
    }                                                                   \
  }

  // prologue: stage chunks 0,1 into lbuf; producer preloads chunk 0 regs
  float4 rA;
  rA = *(const float4*)GADDR(0); *(float4*)&lbuf[0][lidx] = rA;
  rA = *(const float4*)GADDR(1); *(float4*)&lbuf[1][lidx] = rA;
  __syncthreads();
  if (prod) P_PREF(kA, vA, 0);

  for (int c2 = 0; c2 < 32; ++c2) {
    // ======== even phase: ch = 2*c2 ========
    {
      const int ch = 2 * c2;
      if (ch + 2 < 64) rA = *(const float4*)GADDR(ch + 2);
      if (prod) {
        if (ch + 1 < 64) P_PREF(kB, vB, (ch + 1) & 3);  // issue, completes under compute
        P_COMP(kA, vA, 0);                              // chunk ch (even), alcc buf0
      } else {
        if (ch >= 2) C_STORE(ch - 2);
        if (ch >= 1) C_COMP(kB, qB, 1);                 // chunk ch-1 (odd), alcc buf1
        C_PREF(kA, qA, ch & 3);                         // prefetch chunk ch; tail hides under producer
      }
      if (ch + 2 < 64) *(float4*)&lbuf[(ch + 2) & 3][lidx] = rA;  // pre-barrier
      __syncthreads();
    }
    // ======== odd phase: ch = 2*c2 + 1 ========
    {
      const int ch = 2 * c2 + 1;
      if (ch + 2 < 64) rA = *(const float4*)GADDR(ch + 2);
      if (prod) {
        if (ch + 1 < 64) P_PREF(kA, vA, (ch + 1) & 3);
        P_COMP(kB, vB, 1);                              // chunk ch (odd), alcc buf1
      } else {
        if (ch >= 2) C_STORE(ch - 2);
        C_COMP(kA, qA, 0);                              // chunk ch-1 (even), alcc buf0
        C_PREF(kB, qB, ch & 3);                         // prefetch chunk ch
      }
      if (ch + 2 < 64) *(float4*)&lbuf[(ch + 2) & 3][lidx] = rA;  // pre-barrier
      __syncthreads();
    }
  }
  // epilogue (phase 64): consumer computes chunk 63 (odd -> B regs, alcc buf1)
  if (!prod) {
    C_STORE(62);
    C_COMP(kB, qB, 1);
    C_STORE(63);
    float4 o = {s01[0], s01[1], s23[0], s23[1]};
    *(float4*)(Sout + ((size_t)b * NST + r) * NST + j0) = o;
  }
#undef GADDR
#undef P_PREF
#undef C_PREF
#undef P_COMP
#undef C_COMP
#undef C_STORE
}

extern "C" void kernel_launch(void* const* d_in, const int* in_sizes, int n_in,
                              void* d_out, int out_size, void* d_ws, size_t ws_size,
                              hipStream_t stream) {
  const float* x  = (const float*)d_in[0];
  const float* S0 = (const float*)d_in[1];
  const float* Wk = (const float*)d_in[2];
  const float* Wv = (const float*)d_in[3];
  const float* Wq = (const float*)d_in[4];
  const float* Wa = (const float*)d_in[5];
  const float* da = (const float*)d_in[6];
  const float* ba = (const float*)d_in[7];

  float* out  = (float*)d_out;                        // [T,B,64]
  float* Sout = out + (size_t)T_STEPS * BATCH * NST;  // [B,64,64]
  float* projf = (float*)d_ws;                        // [16384][256] f32 = 16 MB
  _Float16* Wc = (_Float16*)((char*)d_ws + (size_t)16384 * 256 * 4);  // 512 KB

  wconv<<<256, 256, 0, stream>>>(Wk, Wv, Wq, Wa, Wc);
  proj_gemm<<<256, 512, 0, stream>>>(x, Wc, projf);
  scan_kernel<<<4 * BATCH, 512, 0, stream>>>(projf, S0, da, ba, out, Sout);
}

// Round 11
// 200.007 us; speedup vs baseline: 1.0237x; 1.0237x over previous
//
#include <hip/hip_runtime.h>
#include <hip/hip_bf16.h>

#define T_STEPS 512
#define BATCH 32
#define NST 64
#define DIM 1024

typedef _Float16 f16x8 __attribute__((ext_vector_type(8)));
typedef _Float16 f16x4 __attribute__((ext_vector_type(4)));
typedef float f32x4 __attribute__((ext_vector_type(4)));
typedef float f32x2 __attribute__((ext_vector_type(2)));

__device__ __forceinline__ void gl_lds16(const void* g, void* l) {
  __builtin_amdgcn_global_load_lds(
      (const __attribute__((address_space(1))) void*)g,
      (__attribute__((address_space(3))) void*)l, 16, 0, 0);
}

// ---------------- W concat + fp16 convert ----------------
__global__ __launch_bounds__(256) void wconv(
    const float* __restrict__ Wk, const float* __restrict__ Wv,
    const float* __restrict__ Wq, const float* __restrict__ Wa,
    _Float16* __restrict__ Wc) {
  const int n = blockIdx.x;
  const int g = n >> 6, r = n & 63;
  const float* W = (g == 0) ? Wk : (g == 1) ? Wq : (g == 2) ? Wv : Wa;
  const float sc = (g == 3) ? -1.44269504088896340736f : 1.0f;
  float4 v = *(const float4*)(W + (size_t)r * DIM + threadIdx.x * 4);
  f16x4 h = {(_Float16)(v.x * sc), (_Float16)(v.y * sc), (_Float16)(v.z * sc),
             (_Float16)(v.w * sc)};
  *(f16x4*)(Wc + (size_t)n * DIM + threadIdx.x * 4) = h;
}

// ---------------- Projection GEMM v2 (fp32 output) ----------------
__global__ __launch_bounds__(512) void proj_gemm(
    const float* __restrict__ x, const _Float16* __restrict__ Wc,
    float* __restrict__ projf) {
  const int m0 = blockIdx.x * 64;
  const int tid = threadIdx.x;
  const int lane = tid & 63, wv = tid >> 6;
  const int wm = wv >> 2, wn = wv & 3;
  const int fm = lane & 15, fq = lane >> 4;

  __shared__ __align__(16) _Float16 Bl[2][256 * 32];  // 2 x 16 KB
  __shared__ __align__(16) _Float16 Al[2][64 * 32];   // 2 x 4 KB

  const int brow = tid >> 2;
  const int bcg = (tid & 3) ^ ((tid >> 3) & 3);
  const _Float16* gB = Wc + (size_t)brow * DIM + bcg * 8;
  const int bdst = tid * 8;

#define STAGE_B(buf, k0)                                          \
  {                                                               \
    _Pragma("unroll") for (int i = 0; i < 2; ++i)                 \
        gl_lds16(gB + (size_t)i * 128 * DIM + (k0),               \
                 &Bl[buf][i * 4096 + bdst]);                      \
  }

  const int arow = tid >> 3;
  const int afc = (tid & 7) * 4;
  const float* gA = x + (size_t)(m0 + arow) * DIM + afc;
  const int awp = arow * 32 + ((((tid >> 1) & 3) ^ ((arow >> 1) & 3)) * 8) +
                  (tid & 1) * 4;

#define LOADX(rr, k0)                          \
  {                                            \
    rr = *(const float4*)(gA + (k0));          \
  }
#define CVT_WRITE_A(buf, rr)                                        \
  {                                                                 \
    f16x4 h = {(_Float16)rr.x, (_Float16)rr.y, (_Float16)rr.z,      \
               (_Float16)rr.w};                                     \
    *(f16x4*)&Al[buf][awp] = h;                                     \
  }

  f32x4 acc[2][4];
#pragma unroll
  for (int mi = 0; mi < 2; ++mi)
#pragma unroll
    for (int ni = 0; ni < 4; ++ni) acc[mi][ni] = (f32x4){0.f, 0.f, 0.f, 0.f};

  const int aswz = (fq ^ ((fm >> 1) & 3)) * 8;
  const int abase = (wm * 32 + fm) * 32 + aswz;
  const int bbase = (wn * 64 + fm) * 32 + aswz;

#define COMPUTE(cb)                                                     \
  {                                                                     \
    f16x8 afr[2], bfr[4];                                               \
    _Pragma("unroll") for (int mi = 0; mi < 2; ++mi)                    \
        afr[mi] = *(const f16x8*)&Al[cb][abase + mi * 16 * 32];         \
    _Pragma("unroll") for (int ni = 0; ni < 4; ++ni)                    \
        bfr[ni] = *(const f16x8*)&Bl[cb][bbase + ni * 16 * 32];         \
    _Pragma("unroll") for (int mi = 0; mi < 2; ++mi)                    \
        _Pragma("unroll") for (int ni = 0; ni < 4; ++ni)                \
            acc[mi][ni] = __builtin_amdgcn_mfma_f32_16x16x32_f16(       \
                afr[mi], bfr[ni], acc[mi][ni], 0, 0, 0);                \
  }

  float4 rE, rO;
  LOADX(rE, 0);
  STAGE_B(0, 0);
  LOADX(rO, 32);
  CVT_WRITE_A(0, rE);
  __syncthreads();

  for (int k2 = 0; k2 < 16; ++k2) {
    STAGE_B(1, (2 * k2 + 1) * 32);
    if (k2 < 15) LOADX(rE, (2 * k2 + 2) * 32);
    CVT_WRITE_A(1, rO);
    COMPUTE(0);
    __syncthreads();
    if (k2 < 15) {
      STAGE_B(0, (2 * k2 + 2) * 32);
      LOADX(rO, (2 * k2 + 3) * 32);
      CVT_WRITE_A(0, rE);
    }
    COMPUTE(1);
    __syncthreads();
  }
#undef STAGE_B
#undef LOADX
#undef CVT_WRITE_A
#undef COMPUTE

#pragma unroll
  for (int mi = 0; mi < 2; ++mi)
#pragma unroll
    for (int ni = 0; ni < 4; ++ni) {
      const int gcol = wn * 64 + ni * 16 + fm;
      const int pcol = gcol < 128 ? gcol
                     : (gcol < 192 ? 128 + 2 * (gcol - 128) : 129 + 2 * (gcol - 192));
#pragma unroll
      for (int r = 0; r < 4; ++r) {
        const int grow = m0 + wm * 32 + mi * 16 + fq * 4 + r;
        projf[(size_t)grow * 256 + pcol] = acc[mi][ni][r];
      }
    }
}

// ---------------- Sequential scan v8: R9 + producer-only reg prefetch -----
// Exact R9 structure (one barrier per chunk, POST-barrier lbuf ds_write,
// consumer with compiler-scheduled in-loop LDS reads, R9 producer math).
// ONLY change: producer double-buffers its chunk operands in registers --
// during phase ch it issues the ds_reads for chunk ch+1 (kB/vB); the
// barrier's lgkmcnt(0) drain completes them for free, so phase ch+1 opens
// with zero memory waits. R10's regression is attributed to its pre-barrier
// lbuf write (re-coupled global-load latency into the barrier drain), which
// this version does NOT have.
__device__ __forceinline__ float red16(float x) {
  int v = __builtin_amdgcn_update_dpp(0, __float_as_int(x), 0xB1, 0xF, 0xF, true);
  x += __int_as_float(v);
  v = __builtin_amdgcn_update_dpp(0, __float_as_int(x), 0x4E, 0xF, 0xF, true);
  x += __int_as_float(v);
  v = __builtin_amdgcn_update_dpp(0, __float_as_int(x), 0x124, 0xF, 0xF, true);
  x += __int_as_float(v);
  v = __builtin_amdgcn_update_dpp(0, __float_as_int(x), 0x128, 0xF, 0xF, true);
  x += __int_as_float(v);
  return x;
}

__global__ __launch_bounds__(512, 1) void scan_kernel(
    const float* __restrict__ projf, const float* __restrict__ S0,
    const float* __restrict__ d_alpha, const float* __restrict__ b_alpha,
    float* __restrict__ out, float* __restrict__ Sout) {
  const int b = blockIdx.x >> 2;
  const int rg = blockIdx.x & 3;
  const int tid = threadIdx.x;
  const bool prod = tid < 256;
  const int ptid = tid & 255;
  const int c = ptid & 15;           // column lane
  const int lr = ptid >> 4;          // local row 0..15
  const int r = rg * 16 + lr;
  const int j0 = c * 4;

  __shared__ __align__(16) float lbuf[4][2048];    // 4-ring x (8 x 256) f32
  __shared__ __align__(16) float2 alcc[2][16][8];  // [buf][lr][si], 2 KB

  constexpr float NL2E = -1.44269504088896340736f;
  f32x2 s01, s23;
  {
    float4 v = *(const float4*)(S0 + ((size_t)b * NST + r) * NST + j0);
    s01 = (f32x2){v.x, v.y}; s23 = (f32x2){v.z, v.w};
  }
  const float da2 = d_alpha[r] * NL2E;
  const float ba2 = b_alpha[r] * NL2E;

  // staging: 512 threads x 1 float4 = one 8-step chunk (8 KB)
  const int sstep = tid >> 6;         // 0..7
  const int soff = (tid & 63) * 4;    // 0..252
  const int lidx = sstep * 256 + soff;
  const float* gp = projf + (size_t)b * 256;
#define GADDR(ch) (gp + (size_t)((ch) * 8 + sstep) * (BATCH * 256) + soff)

  // producer register chunk buffers (A = even chunks, B = odd chunks)
  float4 kA[8], kB[8];
  float2 vA[8], vB[8];
  float ys[8];  // consumer: pending gated outputs

#define P_PREF(kX, vX, slot)                                            \
  {                                                                     \
    const float* Pn = &lbuf[slot][0];                                   \
    _Pragma("unroll") for (int si = 0; si < 8; ++si) {                  \
      kX[si] = *(const float4*)(Pn + si * 256 + j0);                    \
      vX[si] = *(const float2*)(Pn + si * 256 + 128 + 2 * r);           \
    }                                                                   \
  }
#define P_COMP(kX, vX, abuf)                                            \
  {                                                                     \
    float alv[8], ccv[8];                                               \
    _Pragma("unroll") for (int si = 0; si < 8; ++si) {                  \
      const f32x2 k01 = {kX[si].x, kX[si].y};                           \
      const f32x2 k23 = {kX[si].z, kX[si].w};                           \
      f32x2 pa = s01 * k01 + s23 * k23;                                 \
      const float rr = red16(pa[0] + pa[1]);                            \
      float z2 = fmaf(da2, rr, vX[si].y + ba2);                         \
      z2 = __builtin_amdgcn_fmed3f(z2, -43.3f, 43.3f);                  \
      const float e = __builtin_amdgcn_exp2f(z2);        /* exp(-z) */  \
      const float al = __builtin_amdgcn_rcpf(1.f + e);   /* sigmoid */  \
      const float cc = (e * vX[si].x) * al;              /* (1-al)*v */ \
      const f32x2 al2 = {al, al}, cc2 = {cc, cc};                       \
      s01 = al2 * s01 + cc2 * k01;                                      \
      s23 = al2 * s23 + cc2 * k23;                                      \
      alv[si] = al; ccv[si] = cc;                                       \
    }                                                                   \
    if (c == 0) {                                                       \
      float4 w0 = {alv[0], ccv[0], alv[1], ccv[1]};                     \
      float4 w1 = {alv[2], ccv[2], alv[3], ccv[3]};                     \
      float4 w2 = {alv[4], ccv[4], alv[5], ccv[5]};                     \
      float4 w3 = {alv[6], ccv[6], alv[7], ccv[7]};                     \
      float4* wp = (float4*)&alcc[abuf][lr][0];                         \
      wp[0] = w0; wp[1] = w1; wp[2] = w2; wp[3] = w3;                   \
    }                                                                   \
  }
  // consumer: R9-verbatim (alcc first, then bulk lbuf reads, compute)
#define C_COMP(pc)                                                      \
  {                                                                     \
    const float4* ap = (const float4*)&alcc[(pc) & 1][lr][0];           \
    float4 a0 = ap[0], a1 = ap[1], a2 = ap[2], a3 = ap[3];              \
    const float* Pb = &lbuf[(pc) & 3][0];                               \
    float4 kC[8], qC[8];                                                \
    _Pragma("unroll") for (int si = 0; si < 8; ++si) {                  \
      kC[si] = *(const float4*)(Pb + si * 256 + j0);                    \
      qC[si] = *(const float4*)(Pb + si * 256 + 64 + j0);               \
    }                                                                   \
    float2 acv[8];                                                      \
    acv[0] = make_float2(a0.x, a0.y); acv[1] = make_float2(a0.z, a0.w); \
    acv[2] = make_float2(a1.x, a1.y); acv[3] = make_float2(a1.z, a1.w); \
    acv[4] = make_float2(a2.x, a2.y); acv[5] = make_float2(a2.z, a2.w); \
    acv[6] = make_float2(a3.x, a3.y); acv[7] = make_float2(a3.z, a3.w); \
    _Pragma("unroll") for (int si = 0; si < 8; ++si) {                  \
      const f32x2 k01 = {kC[si].x, kC[si].y};                           \
      const f32x2 k23 = {kC[si].z, kC[si].w};                           \
      const f32x2 al2 = {acv[si].x, acv[si].x};                         \
      const f32x2 cc2 = {acv[si].y, acv[si].y};                         \
      s01 = al2 * s01 + cc2 * k01;                                      \
      s23 = al2 * s23 + cc2 * k23;                                      \
      const f32x2 q01 = {qC[si].x, qC[si].y};                           \
      const f32x2 q23 = {qC[si].z, qC[si].w};                           \
      f32x2 hh = s01 * q01 + s23 * q23;                                 \
      const float h = red16(hh[0] + hh[1]);                             \
      const float sg =                                                  \
          __builtin_amdgcn_rcpf(1.f + __builtin_amdgcn_exp2f(h * NL2E)); \
      ys[si] = (h * h) * sg;                                            \
    }                                                                   \
  }
#define C_STORE(pc)                                                     \
  {                                                                     \
    if (c == 0) {                                                       \
      _Pragma("unroll") for (int si = 0; si < 8; ++si)                  \
          out[((size_t)((pc) * 8 + si) * BATCH + b) * NST + r] = ys[si]; \
    }                                                                   \
  }

  // prologue: stage chunks 0,1; producer preloads chunk 0 into A regs
  float4 rA;
  rA = *(const float4*)GADDR(0); *(float4*)&lbuf[0][lidx] = rA;
  rA = *(const float4*)GADDR(1); *(float4*)&lbuf[1][lidx] = rA;
  __syncthreads();
  if (prod) P_PREF(kA, vA, 0);

  for (int c2 = 0; c2 < 32; ++c2) {
    // ======== even phase: ch = 2*c2 ========
    {
      const int ch = 2 * c2;
      if (ch + 2 < 64) rA = *(const float4*)GADDR(ch + 2);
      if (prod) {
        if (ch + 1 < 64) P_PREF(kB, vB, (ch + 1) & 3);  // completes at barrier
        P_COMP(kA, vA, 0);                              // chunk ch, alcc buf0
      } else {
        if (ch >= 2) C_STORE(ch - 2);
        if (ch >= 1) C_COMP(ch - 1);                    // odd chunk, alcc buf1
      }
      __syncthreads();  // single barrier; all waits pre-covered
      if (ch + 2 < 64) *(float4*)&lbuf[(ch + 2) & 3][lidx] = rA;  // POST-barrier
    }
    // ======== odd phase: ch = 2*c2 + 1 ========
    {
      const int ch = 2 * c2 + 1;
      if (ch + 2 < 64) rA = *(const float4*)GADDR(ch + 2);
      if (prod) {
        if (ch + 1 < 64) P_PREF(kA, vA, (ch + 1) & 3);
        P_COMP(kB, vB, 1);                              // chunk ch, alcc buf1
      } else {
        if (ch >= 2) C_STORE(ch - 2);
        C_COMP(ch - 1);                                 // even chunk, alcc buf0
      }
      __syncthreads();
      if (ch + 2 < 64) *(float4*)&lbuf[(ch + 2) & 3][lidx] = rA;  // POST-barrier
    }
  }
  // epilogue (phase 64): consumer computes chunk 63 (alcc buf1, lbuf slot 3)
  if (!prod) {
    C_STORE(62);
    C_COMP(63);
    C_STORE(63);
    float4 o = {s01[0], s01[1], s23[0], s23[1]};
    *(float4*)(Sout + ((size_t)b * NST + r) * NST + j0) = o;
  }
#undef GADDR
#undef P_PREF
#undef P_COMP
#undef C_COMP
#undef C_STORE
}

extern "C" void kernel_launch(void* const* d_in, const int* in_sizes, int n_in,
                              void* d_out, int out_size, void* d_ws, size_t ws_size,
                              hipStream_t stream) {
  const float* x  = (const float*)d_in[0];
  const float* S0 = (const float*)d_in[1];
  const float* Wk = (const float*)d_in[2];
  const float* Wv = (const float*)d_in[3];
  const float* Wq = (const float*)d_in[4];
  const float* Wa = (const float*)d_in[5];
  const float* da = (const float*)d_in[6];
  const float* ba = (const float*)d_in[7];

  float* out  = (float*)d_out;                        // [T,B,64]
  float* Sout = out + (size_t)T_STEPS * BATCH * NST;  // [B,64,64]
  float* projf = (float*)d_ws;                        // [16384][256] f32 = 16 MB
  _Float16* Wc = (_Float16*)((char*)d_ws + (size_t)16384 * 256 * 4);  // 512 KB

  wconv<<<256, 256, 0, stream>>>(Wk, Wv, Wq, Wa, Wc);
  proj_gemm<<<256, 512, 0, stream>>>(x, Wc, projf);
  scan_kernel<<<4 * BATCH, 512, 0, stream>>>(projf, S0, da, ba, out, Sout);
}